// Round 10
// baseline (3452.042 us; speedup 1.0000x reference)
//
#include <hip/hip_runtime.h>
#include <hip/hip_bf16.h>

#define HID 128
#define N_NODES 50000
#define N_HEDGES 10000

// bucket geometry: hyperedge buckets of 16, node buckets of 64; 8 XCD-affinity
// groups per bucket (g = blockIdx&7 ~ XCD under round-robin dispatch).
#define NBE 625            // ceil(10000/16)
#define NBN 782            // ceil(50000/64)
#define SBE (NBE * 8)      // 5000 sub-buckets
#define SBN (NBN * 8)      // 6256 sub-buckets

// ---------------- histogram: degrees + sub-bucket counts ----------------
__global__ void hist_kernel(const int* __restrict__ node_idx,
                            const int* __restrict__ hedge_idx,
                            int* __restrict__ cnt_n, int* __restrict__ cnt_e,
                            int* __restrict__ hsbE, int* __restrict__ hsbN, int nnz) {
    int i = blockIdx.x * 256 + threadIdx.x;
    if (i < nnz) {
        int nd = node_idx[i], he = hedge_idx[i];
        int g = blockIdx.x & 7;
        atomicAdd(&cnt_n[nd], 1);
        atomicAdd(&cnt_e[he], 1);
        atomicAdd(&hsbE[(he >> 4) * 8 + g], 1);
        atomicAdd(&hsbN[(nd >> 6) * 8 + g], 1);
    }
}

// ---------------- exclusive scan of the two sub-bucket count arrays ----------------
__global__ __launch_bounds__(1024) void scan_sb_kernel(
        const int* __restrict__ h0, int* __restrict__ off0, int* __restrict__ cur0, int n0,
        const int* __restrict__ h1, int* __restrict__ off1, int* __restrict__ cur1, int n1) {
    const int* h; int* off; int* cur; int n;
    if (blockIdx.x == 0) { h = h0; off = off0; cur = cur0; n = n0; }
    else                 { h = h1; off = off1; cur = cur1; n = n1; }

    __shared__ int wsum[16];
    __shared__ int carry;
    int t = threadIdx.x, lane = t & 63, w = t >> 6;
    if (t == 0) carry = 0;
    __syncthreads();

    for (int base = 0; base < n; base += 1024) {
        int i = base + t;
        int v = (i < n) ? h[i] : 0;
        int incl = v;
        #pragma unroll
        for (int d = 1; d < 64; d <<= 1) {
            int tmp = __shfl_up(incl, d);
            if (lane >= d) incl += tmp;
        }
        if (lane == 63) wsum[w] = incl;
        __syncthreads();
        if (t == 0) {
            int run = carry;
            #pragma unroll
            for (int k = 0; k < 16; ++k) { int s = wsum[k]; wsum[k] = run; run += s; }
            carry = run;
        }
        __syncthreads();
        int excl = wsum[w] + incl - v;
        if (i < n) { off[i] = excl; cur[i] = excl; }
        __syncthreads();
    }
    if (t == 0) off[n] = carry;
}

// ---------------- bucketed scatter (packed u32 edges, XCD-affinity groups) ----------------
// pack: (key<<16)|payload. node < 65536 (16b), hedge < 16384 (14b) -> both fit.
__global__ void scatter_kernel(const int* __restrict__ node_idx,
                               const int* __restrict__ hedge_idx,
                               int* __restrict__ curE, int* __restrict__ curN,
                               unsigned* __restrict__ sbE, unsigned* __restrict__ sbN, int nnz) {
    int i = blockIdx.x * 256 + threadIdx.x;
    if (i < nnz) {
        int nd = node_idx[i], he = hedge_idx[i];
        int g = blockIdx.x & 7;   // must match hist_kernel's g (same grid shape)
        int se = atomicAdd(&curE[(he >> 4) * 8 + g], 1);
        sbE[se] = ((unsigned)he << 16) | (unsigned)nd;
        int sn = atomicAdd(&curN[(nd >> 6) * 8 + g], 1);
        sbN[sn] = ((unsigned)nd << 16) | (unsigned)he;
    }
}

// ---------------- aggE: e0[he] = (1/deg) * sum of x[node] over bucket edges ----------------
__global__ __launch_bounds__(256) void aggE_kernel(
        const float* __restrict__ x, const unsigned* __restrict__ sbE,
        const int* __restrict__ offE, const int* __restrict__ cnt_e,
        float* __restrict__ e0) {
    __shared__ float acc[16][HID];           // 8 KB
    int t = threadIdx.x, b = blockIdx.x;
    for (int k = t; k < 16 * HID; k += 256) ((float*)acc)[k] = 0.f;
    __syncthreads();

    int s = offE[b * 8], e = offE[b * 8 + 8];   // bucket's 8 group-chunks are contiguous
    int c = t & 127, slot = t >> 7;
    for (int j = s + slot; j < e; j += 2) {
        unsigned p = sbE[j];
        float v = x[(size_t)(p & 0xFFFFu) * HID + c];
        atomicAdd(&acc[(p >> 16) & 15][c], v);
    }
    __syncthreads();

    for (int r = slot; r < 16; r += 2) {
        int he = b * 16 + r;
        int dg = cnt_e[he];
        float inv = dg > 0 ? 1.f / (float)dg : 0.f;
        e0[(size_t)he * HID + c] = acc[r][c] * inv;
    }
}

// ---------------- aggN: u[nd] = (1/deg) * sum of e0[he] over bucket edges ----------------
__global__ __launch_bounds__(256) void aggN_kernel(
        const float* __restrict__ e0, const unsigned* __restrict__ sbN,
        const int* __restrict__ offN, const int* __restrict__ cnt_n,
        float* __restrict__ u) {
    __shared__ float acc[64][HID];           // 32 KB
    int t = threadIdx.x, b = blockIdx.x;
    for (int k = t; k < 64 * HID; k += 256) ((float*)acc)[k] = 0.f;
    __syncthreads();

    int s = offN[b * 8], e = offN[b * 8 + 8];
    int c = t & 127, slot = t >> 7;
    for (int j = s + slot; j < e; j += 2) {
        unsigned p = sbN[j];
        float v = e0[(size_t)(p & 0xFFFFu) * HID + c];
        atomicAdd(&acc[(p >> 16) & 63][c], v);
    }
    __syncthreads();

    for (int r = slot; r < 64; r += 2) {
        int nd = b * 64 + r;
        if (nd < N_NODES) {
            int dg = cnt_n[nd];
            float inv = dg > 0 ? 1.f / (float)dg : 0.f;
            u[(size_t)nd * HID + c] = acc[r][c] * inv;
        }
    }
}

// ---------------- shared GEMM helpers ----------------
#define BR 32

__device__ __forceinline__ void stage_w_swizzled(const float* __restrict__ W, float* wl, int t) {
    // wl[c*128 + ((k4 ^ ((c>>2)&31))<<2) + kj]
    #pragma unroll
    for (int i = 0; i < 16; ++i) {
        int g = t * 4 + i * 1024;
        float4 wv = *(const float4*)(W + g);
        int c = g >> 7;
        int k4 = (g & 127) >> 2;
        *(float4*)(wl + c * HID + ((k4 ^ ((c >> 2) & 31)) << 2)) = wv;
    }
}

// NOTE: unroll capped at 4. Full unroll hoisted ~128 float4 loads, blew past
// 256 VGPRs, spilled accumulators to scratch (rocprof r4: VGPR=256, 4GB FETCH
// + 3GB WRITE per dispatch, VALUBusy 1.5%). r7 confirms fix (GEMMs off top-5).
__device__ __forceinline__ void gemm_acc(const float* wl, const float* const inr[4],
                                         int tc, int c0, float4 acc[4]) {
    #pragma unroll 4
    for (int k4 = 0; k4 < 32; ++k4) {
        int swz = (k4 ^ tc) << 2;
        float4 w0 = *(const float4*)(wl + (c0 + 0) * HID + swz);
        float4 w1 = *(const float4*)(wl + (c0 + 1) * HID + swz);
        float4 w2 = *(const float4*)(wl + (c0 + 2) * HID + swz);
        float4 w3 = *(const float4*)(wl + (c0 + 3) * HID + swz);
        #pragma unroll
        for (int i = 0; i < 4; ++i) {
            float4 uv = *(const float4*)(inr[i] + (k4 << 2));
            acc[i].x += uv.x * w0.x + uv.y * w0.y + uv.z * w0.z + uv.w * w0.w;
            acc[i].y += uv.x * w1.x + uv.y * w1.y + uv.z * w1.z + uv.w * w1.w;
            acc[i].z += uv.x * w2.x + uv.y * w2.y + uv.z * w2.z + uv.w * w2.w;
            acc[i].w += uv.x * w3.x + uv.y * w3.y + uv.z * w3.z + uv.w * w3.w;
        }
    }
}

// ---------------- relu GEMM: out = relu(in @ W^T + b), in-place safe ----------------
__global__ __launch_bounds__(256) void gemm_relu_kernel(
        const float* in, const float* __restrict__ W,
        const float* __restrict__ bias, float* out, int M) {
    __shared__ float wl[HID * HID];      // 64 KB, XOR-swizzled
    int t = threadIdx.x;
    stage_w_swizzled(W, wl, t);
    __syncthreads();

    int tc = t & 31, tr = t >> 5;
    int r0 = blockIdx.x * BR + tr * 4;
    int c0 = tc * 4;

    const float* inr[4];
    #pragma unroll
    for (int i = 0; i < 4; ++i) {
        int r = r0 + i; if (r > M - 1) r = M - 1;
        inr[i] = in + (size_t)r * HID;
    }

    float4 acc[4];
    #pragma unroll
    for (int i = 0; i < 4; ++i) acc[i] = make_float4(0.f, 0.f, 0.f, 0.f);
    gemm_acc(wl, inr, tc, c0, acc);

    __syncthreads();   // in-place: all reads of this block's rows must finish

    float4 bv = *(const float4*)(bias + c0);
    #pragma unroll
    for (int i = 0; i < 4; ++i) {
        int r = r0 + i;
        if (r >= M) continue;
        float4 v = acc[i];
        v.x = fmaxf(v.x + bv.x, 0.f); v.y = fmaxf(v.y + bv.y, 0.f);
        v.z = fmaxf(v.z + bv.z, 0.f); v.w = fmaxf(v.w + bv.w, 0.f);
        *(float4*)(out + (size_t)r * HID + c0) = v;
    }
}

// ---------------- fused mean+logstd GEMM + reparameterization ----------------
// z = noise * exp(h @ Ws^T + bs) + (h @ Wm^T + bm), in-place (h and z alias)
__global__ __launch_bounds__(256) void gemm_vae_kernel(
        const float* h, const float* __restrict__ Wm, const float* __restrict__ bm,
        const float* __restrict__ Ws, const float* __restrict__ bs,
        const float* __restrict__ noise, float* z, int M) {
    __shared__ float wl[HID * HID];      // 64 KB, reused for Wm then Ws
    int t = threadIdx.x;
    int tc = t & 31, tr = t >> 5;
    int r0 = blockIdx.x * BR + tr * 4;
    int c0 = tc * 4;

    const float* inr[4];
    #pragma unroll
    for (int i = 0; i < 4; ++i) {
        int r = r0 + i; if (r > M - 1) r = M - 1;
        inr[i] = h + (size_t)r * HID;
    }

    // pass 1: mean accumulator
    stage_w_swizzled(Wm, wl, t);
    __syncthreads();
    float4 accM[4];
    #pragma unroll
    for (int i = 0; i < 4; ++i) accM[i] = make_float4(0.f, 0.f, 0.f, 0.f);
    gemm_acc(wl, inr, tc, c0, accM);
    __syncthreads();                     // everyone done reading Wm

    // pass 2: logstd accumulator (same LDS buffer)
    stage_w_swizzled(Ws, wl, t);
    __syncthreads();
    float4 accS[4];
    #pragma unroll
    for (int i = 0; i < 4; ++i) accS[i] = make_float4(0.f, 0.f, 0.f, 0.f);
    gemm_acc(wl, inr, tc, c0, accS);

    __syncthreads();                     // in-place: all reads of h rows done

    float4 bmv = *(const float4*)(bm + c0);
    float4 bsv = *(const float4*)(bs + c0);
    #pragma unroll
    for (int i = 0; i < 4; ++i) {
        int r = r0 + i;
        if (r >= M) continue;
        size_t o = (size_t)r * HID + c0;
        float4 nz = *(const float4*)(noise + o);
        float4 m = accM[i], s = accS[i], zv;
        zv.x = nz.x * expf(s.x + bsv.x) + m.x + bmv.x;
        zv.y = nz.y * expf(s.y + bsv.y) + m.y + bmv.y;
        zv.z = nz.z * expf(s.z + bsv.z) + m.z + bmv.z;
        zv.w = nz.w * expf(s.w + bsv.w) + m.w + bmv.w;
        *(float4*)(z + o) = zv;
    }
}

extern "C" void kernel_launch(void* const* d_in, const int* in_sizes, int n_in,
                              void* d_out, int out_size, void* d_ws, size_t ws_size,
                              hipStream_t stream) {
    const float* x      = (const float*)d_in[0];
    const int* node_idx = (const int*)d_in[1];
    const int* hedge_idx= (const int*)d_in[2];
    const float* noise  = (const float*)d_in[3];
    const float* Wc     = (const float*)d_in[4];
    const float* bc     = (const float*)d_in[5];
    const float* Wm     = (const float*)d_in[6];
    const float* bm     = (const float*)d_in[7];
    const float* Ws     = (const float*)d_in[8];
    const float* bs     = (const float*)d_in[9];
    float* out = (float*)d_out;          // doubles as u / h / z buffer
    const int nnz = in_sizes[1];

    // workspace carve-up (256B aligned), total ~18.3 MB
    char* p = (char*)d_ws;
    auto alloc = [&](size_t bytes) -> void* {
        void* r = (void*)p;
        p += (bytes + 255) & ~(size_t)255;
        return r;
    };
    int* cnt_e = (int*)alloc(N_HEDGES * 4);
    int* cnt_n = (int*)alloc(N_NODES * 4);
    int* hsbE  = (int*)alloc(SBE * 4);
    int* hsbN  = (int*)alloc(SBN * 4);
    int* offE  = (int*)alloc((SBE + 1) * 4);
    int* curE  = (int*)alloc(SBE * 4);
    int* offN  = (int*)alloc((SBN + 1) * 4);
    int* curN  = (int*)alloc(SBN * 4);
    unsigned* sbE = (unsigned*)alloc((size_t)nnz * 4);
    unsigned* sbN = (unsigned*)alloc((size_t)nnz * 4);
    float* e0  = (float*)alloc((size_t)N_HEDGES * HID * 4);

    hipMemsetAsync(cnt_e, 0, N_HEDGES * 4, stream);
    hipMemsetAsync(cnt_n, 0, N_NODES * 4, stream);
    hipMemsetAsync(hsbE, 0, SBE * 4, stream);
    hipMemsetAsync(hsbN, 0, SBN * 4, stream);

    int nb = (nnz + 255) / 256;
    hist_kernel<<<nb, 256, 0, stream>>>(node_idx, hedge_idx, cnt_n, cnt_e, hsbE, hsbN, nnz);
    scan_sb_kernel<<<2, 1024, 0, stream>>>(hsbE, offE, curE, SBE, hsbN, offN, curN, SBN);
    scatter_kernel<<<nb, 256, 0, stream>>>(node_idx, hedge_idx, curE, curN, sbE, sbN, nnz);

    aggE_kernel<<<NBE, 256, 0, stream>>>(x, sbE, offE, cnt_e, e0);
    aggN_kernel<<<NBN, 256, 0, stream>>>(e0, sbN, offN, cnt_n, out);

    int gg = (N_NODES + BR - 1) / BR;
    gemm_relu_kernel<<<gg, 256, 0, stream>>>(out, Wc, bc, out, N_NODES);
    gemm_vae_kernel<<<gg, 256, 0, stream>>>(out, Wm, bm, Ws, bs, noise, out, N_NODES);
}